// Round 2
// baseline (513.746 us; speedup 1.0000x reference)
//
#include <hip/hip_runtime.h>

// ---------------- problem constants ----------------
// B=4096 batch, D=2048 dim, H=3 hidden layers, O=1 output
#define BB 4096
#define DD 2048

typedef float f32x4 __attribute__((ext_vector_type(4)));
typedef __bf16 bf16x8 __attribute__((ext_vector_type(8)));

typedef __attribute__((address_space(1))) unsigned int gl_u32;
typedef __attribute__((address_space(3))) unsigned int lds_u32;

#define GLOAD_LDS16(gptr, sptr) \
  __builtin_amdgcn_global_load_lds((gl_u32*)(void*)(gptr), (lds_u32*)(sptr), 16, 0, 0)

__device__ __forceinline__ unsigned short f2bf(float f) {
  unsigned int u = __float_as_uint(f);
  u += 0x7fffu + ((u >> 16) & 1u);   // round-to-nearest-even
  return (unsigned short)(u >> 16);
}

// fast softplus: v_exp_f32 + v_log_f32 (quarter-rate HW ops).
__device__ __forceinline__ float sp(float x) {
  float t = __expf(-fabsf(x));
  return fmaxf(x, 0.0f) + __logf(1.0f + t);
}

__device__ __forceinline__ void prep_w_vec4(
    const float* __restrict__ mu, const float* __restrict__ rho,
    const float* __restrict__ eps, unsigned short* __restrict__ Wh,
    long long i)
{
  float4 m = ((const float4*)mu)[i];
  float4 r = ((const float4*)rho)[i];
  float4 e = ((const float4*)eps)[i];
  ushort4 o;
  o.x = f2bf(m.x + e.x * sp(r.x));
  o.y = f2bf(m.y + e.y * sp(r.y));
  o.z = f2bf(m.z + e.z * sp(r.z));
  o.w = f2bf(m.w + e.w * sp(r.w));
  ((ushort4*)Wh)[i] = o;
}

__device__ __forceinline__ void prep_f32_vec4(
    const float* __restrict__ mu, const float* __restrict__ rho,
    const float* __restrict__ eps, float* __restrict__ out, long long i)
{
  float4 m = ((const float4*)mu)[i];
  float4 r = ((const float4*)rho)[i];
  float4 e = ((const float4*)eps)[i];
  float4 o;
  o.x = m.x + e.x * sp(r.x);
  o.y = m.y + e.y * sp(r.y);
  o.z = m.z + e.z * sp(r.z);
  o.w = m.w + e.w * sp(r.w);
  ((float4*)out)[i] = o;
}

// ---------------- R7: plain-launch grid barrier ----------------
// R6 post-mortem: cooperative launch + cg::grid_sync produced
// NON-DETERMINISTIC garbage under the harness's graph capture. Replace with:
//   - plain <<<512,512>>> launch (graph-capture safe)
//   - own ticket barrier in workspace, explicit agent-scope fences
//     (release fence before arrive -> L2 writeback for cross-XCD publish;
//      acquire fence after wait -> cache invalidate before reading peers)
//   - residency by arithmetic: 512 blocks = 2/CU exactly
//     (launch_bounds(512,4) caps VGPR<=128 -> 16 waves/CU; LDS 2x32K<=160K)
//   - failsafe bounded spin: a broken assumption degrades to wrong-answer,
//     never a hang.
// Ticket scheme needs counter to start at a multiple of nb -> launcher does
// hipMemsetAsync(bar, 0, 64) before the kernel (capture-legal; harness does
// the same for d_out).
__device__ __forceinline__ void grid_barrier(unsigned* bar, unsigned nb) {
  __syncthreads();   // compiler emits s_waitcnt vmcnt(0) before s_barrier:
                     // every wave's global stores are complete (in L2) here.
  if (threadIdx.x == 0) {
    __builtin_amdgcn_fence(__ATOMIC_RELEASE, "agent");  // publish XCD L2 -> HBM
    unsigned v = __hip_atomic_fetch_add(bar, 1u, __ATOMIC_ACQ_REL,
                                        __HIP_MEMORY_SCOPE_AGENT);
    unsigned target = (v / nb + 1u) * nb;
    long long spins = 0;
    while ((int)(__hip_atomic_load(bar, __ATOMIC_RELAXED,
                                   __HIP_MEMORY_SCOPE_AGENT) - target) < 0) {
      __builtin_amdgcn_s_sleep(8);
      if (++spins > (1LL << 21)) break;   // failsafe: never deadlock
    }
    __builtin_amdgcn_fence(__ATOMIC_ACQUIRE, "agent"); // invalidate stale caches
  }
  __syncthreads();
}

// ---------------- GEMM geometry: R3's passing config (UNCHANGED) ---------
// C = relu(A @ W^T + bias). A: 4096x2048 bf16 row-major, W: 2048x2048 bf16.
// 128x128 tile, BK=64, 512 threads = 8 waves (2x4), wave tile 64x32 via 4x2
// grid of 16x16x32 MFMA. global_load_lds(16B) with XOR swizzle folded into
// the global address. XCD-aware remap: patch p=id&7 -> 8x8 tile patch.
struct GemmCoords { int m0, n0, mw, nw; int srow[2], sgc[2]; };

__device__ __forceinline__ GemmCoords gemm_coords(int id, int t) {
  GemmCoords g;
  const int w = t >> 6;
  const int p = id & 7;
  const int i4 = id >> 3;
  const int mt = (p & 3) * 8 + (i4 & 7);    // 0..31
  const int nt = (p >> 2) * 8 + (i4 >> 3);  // 0..15
  g.m0 = mt * 128;
  g.n0 = nt * 128;
  g.mw = (w >> 2) * 64;
  g.nw = (w & 3) * 32;
  #pragma unroll
  for (int i = 0; i < 2; ++i) {
    int c = i * 512 + t;
    g.srow[i] = c >> 3;                // tile row 0..127
    g.sgc[i] = (c & 7) ^ (g.srow[i] & 7);
  }
  return g;
}

__device__ __forceinline__ void gemm_mainloop(
    const unsigned short* __restrict__ A,
    const unsigned short* __restrict__ W,
    unsigned short* sA, unsigned short* sB,
    const GemmCoords& gc, int t, f32x4 (&acc)[4][2])
{
  const int K = DD;
  const int l = t & 63;
  const int lq = l >> 4;
  const int lr = l & 15;
  for (int kt = 0; kt < K; kt += 64) {
    #pragma unroll
    for (int i = 0; i < 2; ++i) {
      int c = i * 512 + t;
      const unsigned short* ga = A + (size_t)(gc.m0 + gc.srow[i]) * K + kt + gc.sgc[i] * 8;
      GLOAD_LDS16(ga, &sA[c * 8]);
      const unsigned short* gb = W + (size_t)(gc.n0 + gc.srow[i]) * K + kt + gc.sgc[i] * 8;
      GLOAD_LDS16(gb, &sB[c * 8]);
    }
    __syncthreads();

    #pragma unroll
    for (int s = 0; s < 2; ++s) {
      bf16x8 af[4], bfr[2];
      int g = s * 4 + lq;
      #pragma unroll
      for (int i = 0; i < 4; ++i) {
        int ra = gc.mw + i * 16 + lr;
        af[i] = *(const bf16x8*)&sA[ra * 64 + (g ^ (ra & 7)) * 8];
      }
      #pragma unroll
      for (int j = 0; j < 2; ++j) {
        int rb = gc.nw + j * 16 + lr;
        bfr[j] = *(const bf16x8*)&sB[rb * 64 + (g ^ (rb & 7)) * 8];
      }
      #pragma unroll
      for (int i = 0; i < 4; ++i)
        #pragma unroll
        for (int j = 0; j < 2; ++j)
          acc[i][j] = __builtin_amdgcn_mfma_f32_16x16x32_bf16(af[i], bfr[j], acc[i][j], 0, 0, 0);
    }
    __syncthreads();
  }
}

__device__ __forceinline__ void gemm_epilogue_store(
    const GemmCoords& gc, int t, f32x4 (&acc)[4][2],
    const float* __restrict__ bias, unsigned short* __restrict__ C)
{
  const int N = DD;
  const int l = t & 63;
  const int lq = l >> 4;
  const int lr = l & 15;
  #pragma unroll
  for (int j = 0; j < 2; ++j) {
    int n = gc.n0 + gc.nw + j * 16 + lr;
    float bv = bias[n];
    #pragma unroll
    for (int i = 0; i < 4; ++i) {
      int mbase = gc.m0 + gc.mw + i * 16 + lq * 4;
      #pragma unroll
      for (int r = 0; r < 4; ++r) {
        float v = fmaxf(acc[i][j][r] + bv, 0.0f);
        C[(size_t)(mbase + r) * N + n] = f2bf(v);
      }
    }
  }
}

// per-block share of one layer's W prep: 2048 vec4 (512 thr x 4)
__device__ __forceinline__ void prep_w_share(
    const float* __restrict__ wmuh, const float* __restrict__ wrhoh,
    const float* __restrict__ epswh, unsigned short* __restrict__ Wh,
    long long layer_base_vec4, int id, int t)
{
  long long base = layer_base_vec4 + (long long)id * 2048 + t;
  #pragma unroll
  for (int j = 0; j < 4; ++j)
    prep_w_vec4(wmuh, wrhoh, epswh, Wh, base + j * 512);
}

// ---------------- persistent mega kernel (plain launch) ----------------
// Stage logic identical to the verified 5-kernel pipeline; only the layer
// boundaries changed from kernel launches to grid_barrier().
// Overlap: blocks i and i+256 likely share a CU (round-robin fill), so
// role=(id>>8)&1 preps layer l+1 weights before vs after its GEMM — prep
// depends only on kernel inputs, so ordering is correctness-neutral.
// d_out rule (R5): OVERWRITE ONLY, single producer — no atomics on d_out.
__global__ __launch_bounds__(512, 4) void mega_kernel(
    const float* __restrict__ x,
    const float* __restrict__ wmuh, const float* __restrict__ wrhoh,
    const float* __restrict__ bmuh, const float* __restrict__ brhoh,
    const float* __restrict__ wmuo, const float* __restrict__ wrhoo,
    const float* __restrict__ bmuo, const float* __restrict__ brhoo,
    const float* __restrict__ epswh, const float* __restrict__ epsbh,
    const float* __restrict__ epswo, const float* __restrict__ epsbo,
    unsigned short* __restrict__ Wh, unsigned short* __restrict__ Xb,
    unsigned short* __restrict__ Ha, unsigned short* __restrict__ Hb,
    float* __restrict__ bh, float* __restrict__ wo,
    float* __restrict__ Pbuf, float* __restrict__ out,
    unsigned* __restrict__ bar)
{
  __shared__ unsigned short sA[128 * 64];
  __shared__ unsigned short sB[128 * 64];

  const int id = blockIdx.x;   // 0..511
  const int t = threadIdx.x;   // 0..511

  // ---- S0: prep W0 -> bf16, x -> bf16, b0 (pure memory, no overlap) ----
  {
    long long wb = (long long)id * 2048 + t;
    #pragma unroll
    for (int j = 0; j < 4; ++j)
      prep_w_vec4(wmuh, wrhoh, epswh, Wh, wb + j * 512);
    long long xb = (long long)id * 4096 + t;
    #pragma unroll
    for (int j = 0; j < 8; ++j) {
      float4 v = ((const float4*)x)[xb + j * 512];
      ushort4 o;
      o.x = f2bf(v.x); o.y = f2bf(v.y); o.z = f2bf(v.z); o.w = f2bf(v.w);
      ((ushort4*)Xb)[xb + j * 512] = o;
    }
    if (id == 0) prep_f32_vec4(bmuh, brhoh, epsbh, bh, t);  // b0
  }
  grid_barrier(bar, 512u);

  const GemmCoords gc = gemm_coords(id, t);
  const int role = (id >> 8) & 1;   // CU pair = (i, i+256)

  // ---- S1: GEMM1 relu(Xb @ W0^T + b0) -> Ha, overlapped with W1/b1 prep --
  {
    if (role) {
      prep_w_share(wmuh, wrhoh, epswh, Wh, 1048576LL, id, t);   // W1
      if (id == 256) prep_f32_vec4(bmuh, brhoh, epsbh, bh, 512 + t);  // b1
    }
    f32x4 acc[4][2] = {};
    gemm_mainloop(Xb, Wh, sA, sB, gc, t, acc);
    gemm_epilogue_store(gc, t, acc, bh, Ha);
    if (!role) {
      prep_w_share(wmuh, wrhoh, epswh, Wh, 1048576LL, id, t);
      if (id == 0) prep_f32_vec4(bmuh, brhoh, epsbh, bh, 512 + t);
    }
  }
  grid_barrier(bar, 512u);

  // ---- S2: GEMM2 relu(Ha @ W1^T + b1) -> Hb, overlapped with W2/b2/wo ----
  {
    if (role) {
      prep_w_share(wmuh, wrhoh, epswh, Wh, 2097152LL, id, t);   // W2
      if (id == 256) prep_f32_vec4(bmuh, brhoh, epsbh, bh, 1024 + t);  // b2
      if (id == 257) prep_f32_vec4(wmuo, wrhoo, epswo, wo, t);         // wo
    }
    f32x4 acc[4][2] = {};
    gemm_mainloop(Ha, Wh + 1 * 4194304, sA, sB, gc, t, acc);
    gemm_epilogue_store(gc, t, acc, bh + DD, Hb);
    if (!role) {
      prep_w_share(wmuh, wrhoh, epswh, Wh, 2097152LL, id, t);
      if (id == 0) prep_f32_vec4(bmuh, brhoh, epsbh, bh, 1024 + t);
      if (id == 1) prep_f32_vec4(wmuo, wrhoo, epswo, wo, t);
    }
  }
  grid_barrier(bar, 512u);

  // ---- S3: GEMM3 + dot with wo -> Pbuf (no atomics, full overwrite) ------
  {
    f32x4 acc[4][2] = {};
    gemm_mainloop(Hb, Wh + 2 * 4194304, sA, sB, gc, t, acc);

    const int l = t & 63;
    const int w = t >> 6;
    const int lq = l >> 4;
    const int lr = l & 15;
    const int nq = w & 3;   // which 32-col quarter this wave handles
    const float* bias = bh + 2 * DD;

    float bv[2], wv[2];
    #pragma unroll
    for (int j = 0; j < 2; ++j) {
      int n = gc.n0 + gc.nw + j * 16 + lr;
      bv[j] = bias[n];
      wv[j] = wo[n];
    }
    float partial[4][4];
    #pragma unroll
    for (int i = 0; i < 4; ++i)
      #pragma unroll
      for (int r = 0; r < 4; ++r)
        partial[i][r] = fmaxf(acc[i][0][r] + bv[0], 0.0f) * wv[0]
                      + fmaxf(acc[i][1][r] + bv[1], 0.0f) * wv[1];

    // butterfly over lr (lane bits 0..3)
    #pragma unroll
    for (int d = 1; d <= 8; d <<= 1)
      #pragma unroll
      for (int i = 0; i < 4; ++i)
        #pragma unroll
        for (int r = 0; r < 4; ++r)
          partial[i][r] += __shfl_xor(partial[i][r], d, 64);

    // cross-wave reduce via LDS (reuse sA; mainloop ended with __syncthreads)
    float* sRed = (float*)sA;   // [128 rows][4 quarters]
    if (lr == 0) {
      #pragma unroll
      for (int i = 0; i < 4; ++i)
        #pragma unroll
        for (int r = 0; r < 4; ++r) {
          int row = gc.mw + i * 16 + lq * 4 + r;   // 0..127 in tile
          sRed[row * 4 + nq] = partial[i][r];
        }
    }
    __syncthreads();
    if (t < 128) {
      float s = sRed[t * 4 + 0] + sRed[t * 4 + 1] + sRed[t * 4 + 2] + sRed[t * 4 + 3];
      int nt = gc.n0 >> 7;
      Pbuf[nt * BB + gc.m0 + t] = s;
    }
  }
  grid_barrier(bar, 512u);

  // ---- S4: out[m] = bo + sum_{nt<16} Pbuf[nt*4096+m] (overwrite-only) ----
  if (id < 8) {
    int m = id * 512 + t;
    float s = bmuo[0] + epsbo[0] * sp(brhoo[0]);
    #pragma unroll
    for (int nt = 0; nt < 16; ++nt)
      s += Pbuf[nt * BB + m];
    out[m] = s;
  }
}

// ---------------- launch ----------------
extern "C" void kernel_launch(void* const* d_in, const int* in_sizes, int n_in,
                              void* d_out, int out_size, void* d_ws, size_t ws_size,
                              hipStream_t stream) {
  const float* x     = (const float*)d_in[0];
  const float* wmuh  = (const float*)d_in[1];
  const float* wrhoh = (const float*)d_in[2];
  const float* bmuh  = (const float*)d_in[3];
  const float* brhoh = (const float*)d_in[4];
  const float* wmuo  = (const float*)d_in[5];
  const float* wrhoo = (const float*)d_in[6];
  const float* bmuo  = (const float*)d_in[7];
  const float* brhoo = (const float*)d_in[8];
  const float* epswh = (const float*)d_in[9];
  const float* epsbh = (const float*)d_in[10];
  const float* epswo = (const float*)d_in[11];
  const float* epsbo = (const float*)d_in[12];

  char* ws = (char*)d_ws;
  unsigned short* Wh = (unsigned short*)(ws);                       // 25165824 B
  unsigned short* Xb = (unsigned short*)(ws + 25165824);            // 16777216 B
  unsigned short* Ha = (unsigned short*)(ws + 25165824 + 16777216);
  unsigned short* Hb = (unsigned short*)(ws + 25165824 + 2 * 16777216);
  float* bh   = (float*)(ws + 25165824 + 3 * 16777216);             // 24576 B
  float* wo   = (float*)(ws + 25165824 + 3 * 16777216 + 24576);     // 8192 B
  float* Pbuf = (float*)(ws + 25165824 + 3 * 16777216 + 24576 + 8192); // 262144 B
  unsigned* bar = (unsigned*)(ws + 25165824 + 3 * 16777216 + 24576 + 8192 + 262144); // 64 B

  // ticket barrier needs counter == multiple of 512 at kernel entry
  hipMemsetAsync(bar, 0, 64, stream);

  mega_kernel<<<512, 512, 0, stream>>>(
      x, wmuh, wrhoh, bmuh, brhoh, wmuo, wrhoo, bmuo, brhoo,
      epswh, epsbh, epswo, epsbo,
      Wh, Xb, Ha, Hb, bh, wo, Pbuf, (float*)d_out, bar);
}

// Round 3
// 313.881 us; speedup vs baseline: 1.6368x; 1.6368x over previous
//
#include <hip/hip_runtime.h>

// ---------------- problem constants ----------------
// B=4096 batch, D=2048 dim, H=3 hidden layers, O=1 output
#define BB 4096
#define DD 2048

typedef float f32x4 __attribute__((ext_vector_type(4)));
typedef __bf16 bf16x8 __attribute__((ext_vector_type(8)));

typedef __attribute__((address_space(1))) unsigned int gl_u32;
typedef __attribute__((address_space(3))) unsigned int lds_u32;

#define GLOAD_LDS16(gptr, sptr) \
  __builtin_amdgcn_global_load_lds((gl_u32*)(void*)(gptr), (lds_u32*)(sptr), 16, 0, 0)

__device__ __forceinline__ unsigned short f2bf(float f) {
  unsigned int u = __float_as_uint(f);
  u += 0x7fffu + ((u >> 16) & 1u);   // round-to-nearest-even
  return (unsigned short)(u >> 16);
}

// fast softplus: v_exp_f32 + v_log_f32 (quarter-rate HW ops).
__device__ __forceinline__ float sp(float x) {
  float t = __expf(-fabsf(x));
  return fmaxf(x, 0.0f) + __logf(1.0f + t);
}

// ---------------- write-through (device-coherent) stores ----------------
// R7 post-mortem: per-block agent fences (buffer_wbl2 walks) + contended
// ACQ_REL RMWs made each grid barrier cost ~55us. R8 removes ALL agent
// fences: producers write inter-stage buffers with agent-scope RELAXED
// atomic stores (write-through to the coherent point). Readers use normal
// cached loads — safe because every inter-stage region is written before
// its first read anywhere (no CU/L2 ever holds a stale copy), and graph
// replays are separated by implicit kernel-boundary flush/invalidate.
__device__ __forceinline__ void st_wt_u64(void* p, unsigned long long v) {
  __hip_atomic_store((unsigned long long*)p, v, __ATOMIC_RELAXED,
                     __HIP_MEMORY_SCOPE_AGENT);
}
__device__ __forceinline__ void st_wt_u32(unsigned* p, unsigned v) {
  __hip_atomic_store(p, v, __ATOMIC_RELAXED, __HIP_MEMORY_SCOPE_AGENT);
}
__device__ __forceinline__ void st_wt_f32(float* p, float v) {
  __hip_atomic_store(p, v, __ATOMIC_RELAXED, __HIP_MEMORY_SCOPE_AGENT);
}
__device__ __forceinline__ void st_wt_u16(unsigned short* p, unsigned short v) {
  __hip_atomic_store(p, v, __ATOMIC_RELAXED, __HIP_MEMORY_SCOPE_AGENT);
}
__device__ __forceinline__ unsigned long long pack_us4(ushort4 o) {
  unsigned long long u;
  __builtin_memcpy(&u, &o, 8);
  return u;
}
__device__ __forceinline__ unsigned long long pack_f2(float a, float b) {
  float t[2] = {a, b};
  unsigned long long u;
  __builtin_memcpy(&u, t, 8);
  return u;
}

__device__ __forceinline__ void prep_w_vec4(
    const float* __restrict__ mu, const float* __restrict__ rho,
    const float* __restrict__ eps, unsigned short* __restrict__ Wh,
    long long i)
{
  float4 m = ((const float4*)mu)[i];
  float4 r = ((const float4*)rho)[i];
  float4 e = ((const float4*)eps)[i];
  ushort4 o;
  o.x = f2bf(m.x + e.x * sp(r.x));
  o.y = f2bf(m.y + e.y * sp(r.y));
  o.z = f2bf(m.z + e.z * sp(r.z));
  o.w = f2bf(m.w + e.w * sp(r.w));
  st_wt_u64(&Wh[i * 4], pack_us4(o));
}

__device__ __forceinline__ void prep_f32_vec4(
    const float* __restrict__ mu, const float* __restrict__ rho,
    const float* __restrict__ eps, float* __restrict__ out, long long i)
{
  float4 m = ((const float4*)mu)[i];
  float4 r = ((const float4*)rho)[i];
  float4 e = ((const float4*)eps)[i];
  float ox = m.x + e.x * sp(r.x);
  float oy = m.y + e.y * sp(r.y);
  float oz = m.z + e.z * sp(r.z);
  float ow = m.w + e.w * sp(r.w);
  st_wt_u64(&out[i * 4], pack_f2(ox, oy));
  st_wt_u64(&out[i * 4 + 2], pack_f2(oz, ow));
}

// ---------------- R8 grid barrier: flag-based, zero RMW, zero fences ----
// Arrival: block b write-through-stores flags[b]=epoch AFTER __syncthreads
// (the barrier's implicit s_waitcnt vmcnt(0) guarantees all the block's WT
// stores are at the coherent point first). Collector (block 0, wave 0)
// polls all 512 flags with 8 coalesced loads/lane, then publishes
// done=epoch; all other blocks poll the single done word. No atomic RMW,
// no agent fence anywhere. Bounded spins: a broken residency assumption
// degrades to a wrong answer, never a hang.
__device__ __forceinline__ void grid_barrier(unsigned* flags, int bix,
                                             unsigned epoch) {
  __syncthreads();
  if (threadIdx.x < 64) {
    unsigned* done = flags + 512;
    if (threadIdx.x == 0) st_wt_u32(&flags[bix], epoch);
    if (bix == 0) {
      long long spins = 0;
      for (;;) {
        bool ok = true;
        #pragma unroll
        for (int j = 0; j < 8; ++j)
          ok &= (__hip_atomic_load(&flags[threadIdx.x * 8 + j],
                                   __ATOMIC_RELAXED,
                                   __HIP_MEMORY_SCOPE_AGENT) >= epoch);
        if (__all(ok)) break;
        if (++spins > (1LL << 20)) break;   // failsafe
        __builtin_amdgcn_s_sleep(2);
      }
      if (threadIdx.x == 0) st_wt_u32(done, epoch);
    } else {
      long long spins = 0;
      while (__hip_atomic_load(done, __ATOMIC_RELAXED,
                               __HIP_MEMORY_SCOPE_AGENT) < epoch) {
        if (++spins > (1LL << 18)) break;   // failsafe
        __builtin_amdgcn_s_sleep(8);
      }
    }
  }
  __syncthreads();
  __builtin_amdgcn_fence(__ATOMIC_ACQUIRE, "workgroup");  // compiler ordering only
}

// ---------------- GEMM geometry: R3's passing config (UNCHANGED) ---------
// C = relu(A @ W^T + bias). A: 4096x2048 bf16 row-major, W: 2048x2048 bf16.
// 128x128 tile, BK=64, 512 threads = 8 waves (2x4), wave tile 64x32 via 4x2
// grid of 16x16x32 MFMA. global_load_lds(16B) with XOR swizzle folded into
// the global address. XCD-aware remap: patch p=id&7 -> 8x8 tile patch.
struct GemmCoords { int m0, n0, mw, nw; int srow[2], sgc[2]; };

__device__ __forceinline__ GemmCoords gemm_coords(int id, int t) {
  GemmCoords g;
  const int w = t >> 6;
  const int p = id & 7;
  const int i4 = id >> 3;
  const int mt = (p & 3) * 8 + (i4 & 7);    // 0..31
  const int nt = (p >> 2) * 8 + (i4 >> 3);  // 0..15
  g.m0 = mt * 128;
  g.n0 = nt * 128;
  g.mw = (w >> 2) * 64;
  g.nw = (w & 3) * 32;
  #pragma unroll
  for (int i = 0; i < 2; ++i) {
    int c = i * 512 + t;
    g.srow[i] = c >> 3;                // tile row 0..127
    g.sgc[i] = (c & 7) ^ (g.srow[i] & 7);
  }
  return g;
}

__device__ __forceinline__ void gemm_mainloop(
    const unsigned short* __restrict__ A,
    const unsigned short* __restrict__ W,
    unsigned short* sA, unsigned short* sB,
    const GemmCoords& gc, int t, f32x4 (&acc)[4][2])
{
  const int K = DD;
  const int l = t & 63;
  const int lq = l >> 4;
  const int lr = l & 15;
  for (int kt = 0; kt < K; kt += 64) {
    #pragma unroll
    for (int i = 0; i < 2; ++i) {
      int c = i * 512 + t;
      const unsigned short* ga = A + (size_t)(gc.m0 + gc.srow[i]) * K + kt + gc.sgc[i] * 8;
      GLOAD_LDS16(ga, &sA[c * 8]);
      const unsigned short* gb = W + (size_t)(gc.n0 + gc.srow[i]) * K + kt + gc.sgc[i] * 8;
      GLOAD_LDS16(gb, &sB[c * 8]);
    }
    __syncthreads();

    #pragma unroll
    for (int s = 0; s < 2; ++s) {
      bf16x8 af[4], bfr[2];
      int g = s * 4 + lq;
      #pragma unroll
      for (int i = 0; i < 4; ++i) {
        int ra = gc.mw + i * 16 + lr;
        af[i] = *(const bf16x8*)&sA[ra * 64 + (g ^ (ra & 7)) * 8];
      }
      #pragma unroll
      for (int j = 0; j < 2; ++j) {
        int rb = gc.nw + j * 16 + lr;
        bfr[j] = *(const bf16x8*)&sB[rb * 64 + (g ^ (rb & 7)) * 8];
      }
      #pragma unroll
      for (int i = 0; i < 4; ++i)
        #pragma unroll
        for (int j = 0; j < 2; ++j)
          acc[i][j] = __builtin_amdgcn_mfma_f32_16x16x32_bf16(af[i], bfr[j], acc[i][j], 0, 0, 0);
    }
    __syncthreads();
  }
}

// epilogue: per-element WT stores (2B each, lane-adjacent n -> 32B bursts)
__device__ __forceinline__ void gemm_epilogue_store(
    const GemmCoords& gc, int t, f32x4 (&acc)[4][2],
    const float* __restrict__ bias, unsigned short* __restrict__ C)
{
  const int N = DD;
  const int l = t & 63;
  const int lq = l >> 4;
  const int lr = l & 15;
  #pragma unroll
  for (int j = 0; j < 2; ++j) {
    int n = gc.n0 + gc.nw + j * 16 + lr;
    float bv = bias[n];
    #pragma unroll
    for (int i = 0; i < 4; ++i) {
      int mbase = gc.m0 + gc.mw + i * 16 + lq * 4;
      #pragma unroll
      for (int r = 0; r < 4; ++r) {
        float v = fmaxf(acc[i][j][r] + bv, 0.0f);
        st_wt_u16(&C[(size_t)(mbase + r) * N + n], f2bf(v));
      }
    }
  }
}

// per-block share of one layer's W prep: 2048 vec4 (512 thr x 4)
__device__ __forceinline__ void prep_w_share(
    const float* __restrict__ wmuh, const float* __restrict__ wrhoh,
    const float* __restrict__ epswh, unsigned short* __restrict__ Wh,
    long long layer_base_vec4, int id, int t)
{
  long long base = layer_base_vec4 + (long long)id * 2048 + t;
  #pragma unroll
  for (int j = 0; j < 4; ++j)
    prep_w_vec4(wmuh, wrhoh, epswh, Wh, base + j * 512);
}

// ---------------- persistent mega kernel (plain launch) ----------------
// Stage logic identical to the verified 5-kernel pipeline; layer boundaries
// are flag grid-barriers. Residency by arithmetic: 512 blocks = 2/CU
// (VGPR<=128 via launch_bounds, LDS 2x32K <= 160K).
// Overlap: blocks i and i+256 share a CU (round-robin fill), role=(id>>8)&1
// preps layer l+1 weights before vs after its GEMM — prep depends only on
// kernel inputs, so ordering is correctness-neutral.
// d_out rule (R5): OVERWRITE ONLY, single producer — no atomics on d_out.
__global__ __launch_bounds__(512, 4) void mega_kernel(
    const float* __restrict__ x,
    const float* __restrict__ wmuh, const float* __restrict__ wrhoh,
    const float* __restrict__ bmuh, const float* __restrict__ brhoh,
    const float* __restrict__ wmuo, const float* __restrict__ wrhoo,
    const float* __restrict__ bmuo, const float* __restrict__ brhoo,
    const float* __restrict__ epswh, const float* __restrict__ epsbh,
    const float* __restrict__ epswo, const float* __restrict__ epsbo,
    unsigned short* __restrict__ Wh, unsigned short* __restrict__ Xb,
    unsigned short* __restrict__ Ha, unsigned short* __restrict__ Hb,
    float* __restrict__ bh, float* __restrict__ wo,
    float* __restrict__ Pbuf, float* __restrict__ out,
    unsigned* __restrict__ flags)
{
  __shared__ unsigned short sA[128 * 64];
  __shared__ unsigned short sB[128 * 64];

  const int id = blockIdx.x;   // 0..511
  const int t = threadIdx.x;   // 0..511

  // ---- S0: prep W0 -> bf16, x -> bf16, b0 (pure memory, no overlap) ----
  {
    long long wb = (long long)id * 2048 + t;
    #pragma unroll
    for (int j = 0; j < 4; ++j)
      prep_w_vec4(wmuh, wrhoh, epswh, Wh, wb + j * 512);
    long long xb = (long long)id * 4096 + t;
    #pragma unroll
    for (int j = 0; j < 8; ++j) {
      float4 v = ((const float4*)x)[xb + j * 512];
      ushort4 o;
      o.x = f2bf(v.x); o.y = f2bf(v.y); o.z = f2bf(v.z); o.w = f2bf(v.w);
      st_wt_u64(&Xb[(xb + j * 512) * 4], pack_us4(o));
    }
    if (id == 0) prep_f32_vec4(bmuh, brhoh, epsbh, bh, t);  // b0
  }
  grid_barrier(flags, id, 1u);

  const GemmCoords gc = gemm_coords(id, t);
  const int role = (id >> 8) & 1;   // CU pair = (i, i+256)

  // ---- S1: GEMM1 relu(Xb @ W0^T + b0) -> Ha, overlapped with W1/b1 prep --
  {
    if (role) {
      prep_w_share(wmuh, wrhoh, epswh, Wh, 1048576LL, id, t);   // W1
      if (id == 256) prep_f32_vec4(bmuh, brhoh, epsbh, bh, 512 + t);  // b1
    }
    f32x4 acc[4][2] = {};
    gemm_mainloop(Xb, Wh, sA, sB, gc, t, acc);
    gemm_epilogue_store(gc, t, acc, bh, Ha);
    if (!role) {
      prep_w_share(wmuh, wrhoh, epswh, Wh, 1048576LL, id, t);
      if (id == 0) prep_f32_vec4(bmuh, brhoh, epsbh, bh, 512 + t);
    }
  }
  grid_barrier(flags, id, 2u);

  // ---- S2: GEMM2 relu(Ha @ W1^T + b1) -> Hb, overlapped with W2/b2/wo ----
  {
    if (role) {
      prep_w_share(wmuh, wrhoh, epswh, Wh, 2097152LL, id, t);   // W2
      if (id == 256) prep_f32_vec4(bmuh, brhoh, epsbh, bh, 1024 + t);  // b2
      if (id == 257) prep_f32_vec4(wmuo, wrhoo, epswo, wo, t);         // wo
    }
    f32x4 acc[4][2] = {};
    gemm_mainloop(Ha, Wh + 1 * 4194304, sA, sB, gc, t, acc);
    gemm_epilogue_store(gc, t, acc, bh + DD, Hb);
    if (!role) {
      prep_w_share(wmuh, wrhoh, epswh, Wh, 2097152LL, id, t);
      if (id == 0) prep_f32_vec4(bmuh, brhoh, epsbh, bh, 1024 + t);
      if (id == 1) prep_f32_vec4(wmuo, wrhoo, epswo, wo, t);
    }
  }
  grid_barrier(flags, id, 3u);

  // ---- S3: GEMM3 + dot with wo -> Pbuf (no atomics, full overwrite) ------
  {
    f32x4 acc[4][2] = {};
    gemm_mainloop(Hb, Wh + 2 * 4194304, sA, sB, gc, t, acc);

    const int l = t & 63;
    const int w = t >> 6;
    const int lq = l >> 4;
    const int lr = l & 15;
    const int nq = w & 3;   // which 32-col quarter this wave handles
    const float* bias = bh + 2 * DD;

    float bv[2], wv[2];
    #pragma unroll
    for (int j = 0; j < 2; ++j) {
      int n = gc.n0 + gc.nw + j * 16 + lr;
      bv[j] = bias[n];
      wv[j] = wo[n];
    }
    float partial[4][4];
    #pragma unroll
    for (int i = 0; i < 4; ++i)
      #pragma unroll
      for (int r = 0; r < 4; ++r)
        partial[i][r] = fmaxf(acc[i][0][r] + bv[0], 0.0f) * wv[0]
                      + fmaxf(acc[i][1][r] + bv[1], 0.0f) * wv[1];

    // butterfly over lr (lane bits 0..3)
    #pragma unroll
    for (int d = 1; d <= 8; d <<= 1)
      #pragma unroll
      for (int i = 0; i < 4; ++i)
        #pragma unroll
        for (int r = 0; r < 4; ++r)
          partial[i][r] += __shfl_xor(partial[i][r], d, 64);

    // cross-wave reduce via LDS (reuse sA; mainloop ended with __syncthreads)
    float* sRed = (float*)sA;   // [128 rows][4 quarters]
    if (lr == 0) {
      #pragma unroll
      for (int i = 0; i < 4; ++i)
        #pragma unroll
        for (int r = 0; r < 4; ++r) {
          int row = gc.mw + i * 16 + lq * 4 + r;   // 0..127 in tile
          sRed[row * 4 + nq] = partial[i][r];
        }
    }
    __syncthreads();
    if (t < 128) {
      float s = sRed[t * 4 + 0] + sRed[t * 4 + 1] + sRed[t * 4 + 2] + sRed[t * 4 + 3];
      int nt = gc.n0 >> 7;
      st_wt_f32(&Pbuf[nt * BB + gc.m0 + t], s);
    }
  }
  grid_barrier(flags, id, 4u);

  // ---- S4: out[m] = bo + sum_{nt<16} Pbuf[nt*4096+m] (overwrite-only) ----
  if (id < 8) {
    int m = id * 512 + t;
    float s = bmuo[0] + epsbo[0] * sp(brhoo[0]);
    #pragma unroll
    for (int nt = 0; nt < 16; ++nt)
      s += Pbuf[nt * BB + m];
    out[m] = s;
  }
}

// ---------------- launch ----------------
extern "C" void kernel_launch(void* const* d_in, const int* in_sizes, int n_in,
                              void* d_out, int out_size, void* d_ws, size_t ws_size,
                              hipStream_t stream) {
  const float* x     = (const float*)d_in[0];
  const float* wmuh  = (const float*)d_in[1];
  const float* wrhoh = (const float*)d_in[2];
  const float* bmuh  = (const float*)d_in[3];
  const float* brhoh = (const float*)d_in[4];
  const float* wmuo  = (const float*)d_in[5];
  const float* wrhoo = (const float*)d_in[6];
  const float* bmuo  = (const float*)d_in[7];
  const float* brhoo = (const float*)d_in[8];
  const float* epswh = (const float*)d_in[9];
  const float* epsbh = (const float*)d_in[10];
  const float* epswo = (const float*)d_in[11];
  const float* epsbo = (const float*)d_in[12];

  char* ws = (char*)d_ws;
  unsigned short* Wh = (unsigned short*)(ws);                       // 25165824 B
  unsigned short* Xb = (unsigned short*)(ws + 25165824);            // 16777216 B
  unsigned short* Ha = (unsigned short*)(ws + 25165824 + 16777216);
  unsigned short* Hb = (unsigned short*)(ws + 25165824 + 2 * 16777216);
  float* bh   = (float*)(ws + 25165824 + 3 * 16777216);             // 24576 B
  float* wo   = (float*)(ws + 25165824 + 3 * 16777216 + 24576);     // 8192 B
  float* Pbuf = (float*)(ws + 25165824 + 3 * 16777216 + 24576 + 8192); // 262144 B
  unsigned* flags = (unsigned*)(ws + 25165824 + 3 * 16777216 + 24576 + 8192 + 262144); // 4096 B

  // flag barrier needs flags[] < 1 at kernel entry (epochs are 1..4)
  hipMemsetAsync(flags, 0, 4096, stream);

  mega_kernel<<<512, 512, 0, stream>>>(
      x, wmuh, wrhoh, bmuh, brhoh, wmuo, wrhoo, bmuo, brhoo,
      epswh, epsbh, epswo, epsbo,
      Wh, Xb, Ha, Hb, bh, wo, Pbuf, (float*)d_out, flags);
}